// Round 12
// baseline (489.272 us; speedup 1.0000x reference)
//
#include <hip/hip_runtime.h>
#include <hip/hip_bf16.h>

typedef __hip_bfloat16 bf16;
typedef short bf16x8 __attribute__((ext_vector_type(8)));
typedef short short4v __attribute__((ext_vector_type(4)));
typedef float f32x4 __attribute__((ext_vector_type(4)));

#define B_ 2
#define T_ 2048
#define C_ 768
#define H_ 12
#define HS_ 64
#define M_ (B_ * T_)              // 4096
#define XN_ (B_ * T_ * C_)        // 3145728
#define WN_ (C_ * C_)             // 589824
#define SCALE_ 0.036084391824351615f      // 1/sqrt(768)
#define SCALE_L2E_ 0.05205762071471043f   // SCALE * log2(e)

__device__ inline short bf16bits(float f) {
    union { bf16 b; short s; } u; u.b = __float2bfloat16(f); return u.s;
}

__device__ inline void load_lds16(const void* g, void* l) {
    __builtin_amdgcn_global_load_lds(
        (const __attribute__((address_space(1))) unsigned int*)g,
        (__attribute__((address_space(3))) unsigned int*)l, 16, 0, 0);
}

// fp32 -> bf16 for x, w_u, w_v, w_p in one pass (4 elems/thread).
// Block 0 also zeroes the flash chunk-counters (768 ints) -- stream order
// guarantees this is visible before flash_part launches.
__global__ __launch_bounds__(256) void cvt_all(
    const float* __restrict__ x,  const float* __restrict__ wu,
    const float* __restrict__ wv, const float* __restrict__ wp,
    bf16* __restrict__ Xb,  bf16* __restrict__ Wub,
    bf16* __restrict__ Wvb, bf16* __restrict__ Wpb, int* __restrict__ Cnt)
{
    if (blockIdx.x == 0) {
#pragma unroll
        for (int k = 0; k < 3; ++k) Cnt[threadIdx.x * 3 + k] = 0;
    }
    const long e = (long)(blockIdx.x * 256 + threadIdx.x) * 4;
    const float* src; bf16* dst; long off;
    if (e < XN_)                { src = x;  dst = Xb;  off = e; }
    else if (e < XN_ + WN_)     { src = wu; dst = Wub; off = e - XN_; }
    else if (e < XN_ + 2*WN_)   { src = wv; dst = Wvb; off = e - XN_ - WN_; }
    else                        { src = wp; dst = Wpb; off = e - XN_ - 2L*WN_; }
    f32x4 v = *(const f32x4*)(src + off);
    short4v o;
#pragma unroll
    for (int i = 0; i < 4; ++i) o[i] = bf16bits(v[i]);
    *(short4v*)(dst + off) = o;
}

// sigma^-1 for the PV key permutation: tau bits [u|h|q1 q0|r1 r0] -> [u|q1 q0|h|r1 r0]
__device__ inline int sig_inv(int tau) {
    return (tau & 0x23) | ((tau & 0x10) >> 2) | ((tau & 0x0C) << 1);
}

// Fused U/V projection, 64x128 tile, grid (M/64, 12) = 768 blocks (3/CU).
// by<6 -> U tile scaled by SCALE*log2e (exp2-domain attention);
// by>=6 -> V scattered to sigma/swizzled Vt.
__global__ __launch_bounds__(256) void gemm_uv(
    const bf16* __restrict__ Xb, const bf16* __restrict__ Wu,
    const bf16* __restrict__ Wv, const float* __restrict__ bu,
    const float* __restrict__ bv, bf16* __restrict__ U, bf16* __restrict__ Vt)
{
    __shared__ __align__(16) short tA[64 * 64];    // 8 KB
    __shared__ __align__(16) short tB[128 * 64];   // 16 KB

    const int tid = threadIdx.x;
    const int w = tid >> 6, lane = tid & 63;
    const int nl = lane & 15, quad = lane >> 4;
    const int m0 = blockIdx.x * 64;
    const bool isV = blockIdx.y >= 6;
    const int n0 = (isV ? blockIdx.y - 6 : blockIdx.y) * 128;
    const bf16* Wb = isV ? Wv : Wu;
    const float* bias = isV ? bv : bu;

    f32x4 acc[4][2];
#pragma unroll
    for (int a = 0; a < 4; ++a)
#pragma unroll
        for (int t = 0; t < 2; ++t) acc[a][t] = f32x4{0, 0, 0, 0};

    for (int k0 = 0; k0 < C_; k0 += 64) {
#pragma unroll
        for (int i = 0; i < 2; ++i) {           // A tile: 512 chunks
            const int g = i * 256 + tid;
            const int row = g >> 3, kp = g & 7;
            load_lds16(Xb + (size_t)(m0 + row) * C_ + k0 + (kp ^ (row & 7)) * 8,
                       (char*)tA + g * 16);
        }
#pragma unroll
        for (int i = 0; i < 4; ++i) {           // B tile: 1024 chunks
            const int g = i * 256 + tid;
            const int row = g >> 3, kp = g & 7;
            load_lds16(Wb + (size_t)(n0 + row) * C_ + k0 + (kp ^ (row & 7)) * 8,
                       (char*)tB + g * 16);
        }
        __syncthreads();
#pragma unroll
        for (int half = 0; half < 2; ++half) {
            bf16x8 af[4], bfr[2];
#pragma unroll
            for (int a = 0; a < 4; ++a) {
                const int row = a * 16 + nl;
                af[a] = *(const bf16x8*)((const char*)tA + row * 128 + (((half * 4 + quad) ^ (nl & 7)) * 16));
            }
#pragma unroll
            for (int t = 0; t < 2; ++t) {
                const int row = w * 32 + t * 16 + nl;
                bfr[t] = *(const bf16x8*)((const char*)tB + row * 128 + (((half * 4 + quad) ^ (nl & 7)) * 16));
            }
#pragma unroll
            for (int a = 0; a < 4; ++a)
#pragma unroll
                for (int t = 0; t < 2; ++t)
                    acc[a][t] = __builtin_amdgcn_mfma_f32_16x16x32_bf16(af[a], bfr[t], acc[a][t], 0, 0, 0);
        }
        __syncthreads();
    }

#pragma unroll
    for (int a = 0; a < 4; ++a) {
#pragma unroll
        for (int t = 0; t < 2; ++t) {
            const int col = n0 + w * 32 + t * 16 + nl;
            const float bv_ = bias[col];
#pragma unroll
            for (int r = 0; r < 4; ++r) {
                const int mrow = m0 + a * 16 + quad * 4 + r;
                if (isV) {
                    const float v = acc[a][t][r] + bv_;
                    const int bb = mrow / T_, tt = mrow % T_;
                    const int hh = col / HS_, dd = col % HS_;
                    const int lam = sig_inv(tt & 63);
                    const int pos = (tt & ~63) + (((lam >> 3) ^ (dd & 7)) * 8) + (lam & 7);
                    Vt[(((size_t)bb * H_ + hh) * HS_ + dd) * T_ + pos] = __float2bfloat16(v);
                } else {
                    const float v = (acc[a][t][r] + bv_) * SCALE_L2E_;
                    U[(size_t)mrow * C_ + col] = __float2bfloat16(v);
                }
            }
        }
    }
}

// proj GEMM: 64x64 tile, grid (M/64, C/64) = (64,12) = 768 blocks (3/CU).
__global__ __launch_bounds__(256) void gemm_proj(
    const bf16* __restrict__ A, const bf16* __restrict__ Wb,
    const float* __restrict__ bias, float* __restrict__ Y)
{
    __shared__ __align__(16) short tA[64 * 64];
    __shared__ __align__(16) short tB[64 * 64];

    const int tid = threadIdx.x;
    const int w = tid >> 6, lane = tid & 63;
    const int nl = lane & 15, quad = lane >> 4;
    const int m0 = blockIdx.x * 64, n0 = blockIdx.y * 64;

    f32x4 acc[4];
#pragma unroll
    for (int t = 0; t < 4; ++t) acc[t] = f32x4{0, 0, 0, 0};

    for (int k0 = 0; k0 < C_; k0 += 64) {
#pragma unroll
        for (int i = 0; i < 2; ++i) {
            const int g = i * 256 + tid;
            const int row = g >> 3, kp = g & 7;
            const int kc = (kp ^ (row & 7)) * 8;
            load_lds16(A  + (size_t)(m0 + row) * C_ + k0 + kc, (char*)tA + g * 16);
            load_lds16(Wb + (size_t)(n0 + row) * C_ + k0 + kc, (char*)tB + g * 16);
        }
        __syncthreads();
#pragma unroll
        for (int half = 0; half < 2; ++half) {
            const int row = w * 16 + nl;
            bf16x8 af = *(const bf16x8*)((const char*)tA + row * 128 + (((half * 4 + quad) ^ (nl & 7)) * 16));
#pragma unroll
            for (int t = 0; t < 4; ++t) {
                const int brow = t * 16 + nl;
                bf16x8 bfr = *(const bf16x8*)((const char*)tB + brow * 128 + (((half * 4 + quad) ^ (nl & 7)) * 16));
                acc[t] = __builtin_amdgcn_mfma_f32_16x16x32_bf16(af, bfr, acc[t], 0, 0, 0);
            }
        }
        __syncthreads();
    }

#pragma unroll
    for (int t = 0; t < 4; ++t) {
        const int col = n0 + t * 16 + nl;
        const float bv = bias[col];
#pragma unroll
        for (int r = 0; r < 4; ++r) {
            const int mrow = m0 + w * 16 + quad * 4 + r;
            Y[(size_t)mrow * C_ + col] = acc[t][r] + bv;
        }
    }
}

// Flash partial + fused last-block combine. Block = (64-query tile a,
// key-chunk c of <=8 K-tiles); additive (O,l) partials (exp2 domain, raw
// v_exp_f32, v_perm_b32 bf16 pack). Single-chunk qtiles (i<8) write Yw
// directly. Multi-chunk: write bf16 O partial + fp32 l, fence, atomicAdd a
// per-(b,h,a) counter; the LAST block re-reads all chunks and writes the
// normalized Yw -- removes the separate combine kernel and its launch gap.
__global__ __launch_bounds__(256) void flash_part(
    const bf16* __restrict__ U, const bf16* __restrict__ Xb,
    const bf16* __restrict__ Vt, bf16* __restrict__ PartO,
    float* __restrict__ PartL, bf16* __restrict__ Yw, int* __restrict__ Cnt)
{
    __shared__ __align__(16) short kbuf[2][64 * 64];
    __shared__ __align__(16) short vbuf[2][64 * 64];
    __shared__ int lastf;

    const int i = 79 - blockIdx.x;            // heavy chunks first
    int a, c;
    if (i < 8)       { a = i;                c = 0; }
    else if (i < 24) { a = 8  + (i - 8)  / 2; c = (i - 8)  % 2; }
    else if (i < 48) { a = 16 + (i - 24) / 3; c = (i - 24) % 3; }
    else             { a = 24 + (i - 48) / 4; c = (i - 48) % 4; }
    const int kt0 = c * 8, kt1 = min(c * 8 + 7, a);

    const int h = blockIdx.y, b = blockIdx.z;
    const int w = threadIdx.x >> 6, lane = threadIdx.x & 63;
    const int nl = lane & 15, quad = lane >> 4;

    const size_t xbase = (size_t)b * T_ * C_ + (size_t)h * HS_;
    const size_t vtb   = ((size_t)(b * H_ + h)) * HS_ * T_;
    const int q0w = a * 64 + w * 16;

    bf16x8 qb0, qb1;
    {
        const bf16* qp = U + xbase + (size_t)(q0w + nl) * C_;
        qb0 = *(const bf16x8*)(qp + quad * 8);
        qb1 = *(const bf16x8*)(qp + 32 + quad * 8);
    }

    bf16x8 ones;
#pragma unroll
    for (int k = 0; k < 8; ++k) ones[k] = (short)0x3F80;

    f32x4 o[4];
#pragma unroll
    for (int g = 0; g < 4; ++g) o[g] = f32x4{0, 0, 0, 0};
    f32x4 lacc = f32x4{0, 0, 0, 0};

    auto stage = [&](int kt_, int pbuf_) {
        short* kb_ = kbuf[pbuf_]; short* vb_ = vbuf[pbuf_];
#pragma unroll
        for (int i_ = 0; i_ < 2; ++i_) {
            const int g_ = (w * 2 + i_) * 64 + lane;
            const int rw_ = g_ >> 3, kp_ = g_ & 7;
            load_lds16(Xb + xbase + (size_t)(kt_ * 64 + rw_) * C_ + ((kp_ ^ (rw_ & 7)) * 8),
                       (char*)kb_ + (w * 2 + i_) * 1024);
            load_lds16(Vt + vtb + (size_t)rw_ * T_ + kt_ * 64 + kp_ * 8,
                       (char*)vb_ + (w * 2 + i_) * 1024);
        }
    };

    stage(kt0, 0);
    int pb = 0;
    for (int kt = kt0; kt <= kt1; ++kt) {
        __syncthreads();                       // drains stage(kt)
        if (kt < kt1) stage(kt + 1, pb ^ 1);   // prefetch overlaps compute

        const short* kb  = kbuf[pb];
        const short* vbp = vbuf[pb];
        const bool dg = (kt == a);             // diagonal tile (last chunk only)

        // S^T = K.Q^T: lane (quad,nl) reg r = S[key=16t+4quad+r][q=q0w+nl]
        f32x4 s[4];
#pragma unroll
        for (int t = 0; t < 4; ++t) {
            s[t] = f32x4{0, 0, 0, 0};
            if (!dg || t <= w) {
                const int key = t * 16 + nl;
                bf16x8 k0 = *(const bf16x8*)((const char*)kb + key * 128 + (((0 + quad) ^ (nl & 7)) * 16));
                bf16x8 k1 = *(const bf16x8*)((const char*)kb + key * 128 + (((4 + quad) ^ (nl & 7)) * 16));
                s[t] = __builtin_amdgcn_mfma_f32_16x16x32_bf16(k0, qb0, s[t], 0, 0, 0);
                s[t] = __builtin_amdgcn_mfma_f32_16x16x32_bf16(k1, qb1, s[t], 0, 0, 0);
            }
        }

        // p = 2^s via raw v_exp_f32; round-half-up to bf16 and pack pairs
        // with v_perm_b32 (sel 0x07060302 takes the two hi16s).
        unsigned pw[8];
#pragma unroll
        for (int t = 0; t < 4; ++t) {
            float p[4];
#pragma unroll
            for (int r = 0; r < 4; ++r) {
                if (!dg || t <= w) {
                    p[r] = __builtin_amdgcn_exp2f(s[t][r]);
                    if (dg && t == w && (4 * quad + r > nl)) p[r] = 0.f;
                } else {
                    p[r] = 0.f;
                }
            }
#pragma unroll
            for (int hp = 0; hp < 2; ++hp) {
                const unsigned b0 = __float_as_uint(p[hp * 2])     + 0x8000u;
                const unsigned b1 = __float_as_uint(p[hp * 2 + 1]) + 0x8000u;
                pw[t * 2 + hp] = __builtin_amdgcn_perm(b1, b0, 0x07060302u);
            }
        }
        union { unsigned u[4]; bf16x8 v; } cv0, cv1;
#pragma unroll
        for (int k = 0; k < 4; ++k) { cv0.u[k] = pw[k]; cv1.u[k] = pw[4 + k]; }
        const bf16x8 pa0 = cv0.v, pa1 = cv1.v;

        // l += P.1 ; O += P.V (sigma-permuted keys match Vt layout)
        lacc = __builtin_amdgcn_mfma_f32_16x16x32_bf16(pa0, ones, lacc, 0, 0, 0);
        lacc = __builtin_amdgcn_mfma_f32_16x16x32_bf16(pa1, ones, lacc, 0, 0, 0);
#pragma unroll
        for (int g = 0; g < 4; ++g) {
            const int d = g * 16 + nl;
            bf16x8 v0 = *(const bf16x8*)((const char*)vbp + d * 128 + (((0 + quad) ^ (nl & 7)) * 16));
            bf16x8 v1 = *(const bf16x8*)((const char*)vbp + d * 128 + (((4 + quad) ^ (nl & 7)) * 16));
            o[g] = __builtin_amdgcn_mfma_f32_16x16x32_bf16(pa0, v0, o[g], 0, 0, 0);
            o[g] = __builtin_amdgcn_mfma_f32_16x16x32_bf16(pa1, v1, o[g], 0, 0, 0);
        }
        pb ^= 1;
    }

    if (i < 8) {
        // single chunk: normalize and write Yw directly (token-major)
#pragma unroll
        for (int r = 0; r < 4; ++r) {
            const float inv_l = 1.f / lacc[r];
            const size_t yrow = xbase + (size_t)(q0w + quad * 4 + r) * C_;
#pragma unroll
            for (int g = 0; g < 4; ++g)
                Yw[yrow + g * 16 + nl] = __float2bfloat16(o[g][r] * inv_l);
        }
        return;
    }

    // bf16 O partial (64x64) + fp32 l (64)
    bf16* slot = PartO + (size_t)((b * H_ + h) * 80 + i) * 4096;
#pragma unroll
    for (int g = 0; g < 4; ++g)
#pragma unroll
        for (int r = 0; r < 4; ++r)
            slot[(w * 16 + quad * 4 + r) * 64 + g * 16 + nl] = __float2bfloat16(o[g][r]);
    if (nl == 0) {
        float* lslot = PartL + (size_t)((b * H_ + h) * 80 + i) * 64;
#pragma unroll
        for (int r = 0; r < 4; ++r)
            lslot[w * 16 + quad * 4 + r] = lacc[r];
    }

    // last block for this (b,h,a) combines all chunks
    __threadfence();
    if (threadIdx.x == 0) {
        const int nch_ = (a >> 3) + 1;
        const int old = atomicAdd(&Cnt[(b * H_ + h) * 32 + a], 1);
        lastf = (old == nch_ - 1);
    }
    __syncthreads();
    if (!lastf) return;
    __threadfence();                           // acquire other blocks' stores

    const int nch = (a >> 3) + 1;
    const int base = i - c;
    const int tid = threadIdx.x;
    const int q = tid >> 2, d0 = (tid & 3) * 16;
    const size_t bh80 = (size_t)(b * H_ + h) * 80 + base;

    float facc[16];
#pragma unroll
    for (int j = 0; j < 16; ++j) facc[j] = 0.f;
    float l = 0.f;
    for (int cc = 0; cc < nch; ++cc) {
        const bf16* sp = PartO + (bh80 + cc) * 4096 + q * 64 + d0;
#pragma unroll
        for (int v = 0; v < 2; ++v) {
            bf16x8 pk = *(const bf16x8*)(sp + v * 8);
#pragma unroll
            for (int k = 0; k < 8; ++k) {
                union { short s2; bf16 b2; } u2; u2.s2 = pk[k];
                facc[v * 8 + k] += __bfloat162float(u2.b2);
            }
        }
        l += PartL[(bh80 + cc) * 64 + q];
    }
    const float inv = 1.f / l;
    bf16* yp = Yw + ((size_t)(b * T_ + a * 64 + q)) * C_ + h * HS_ + d0;
#pragma unroll
    for (int v = 0; v < 4; ++v) {
        short4v ov;
#pragma unroll
        for (int k = 0; k < 4; ++k) ov[k] = bf16bits(facc[v * 4 + k] * inv);
        *(short4v*)(yp + v * 4) = ov;
    }
}

extern "C" void kernel_launch(void* const* d_in, const int* in_sizes, int n_in,
                              void* d_out, int out_size, void* d_ws, size_t ws_size,
                              hipStream_t stream) {
    const float* x   = (const float*)d_in[0];
    const float* w_u = (const float*)d_in[1];
    const float* b_u = (const float*)d_in[2];
    const float* w_v = (const float*)d_in[3];
    const float* b_v = (const float*)d_in[4];
    const float* w_p = (const float*)d_in[5];
    const float* b_p = (const float*)d_in[6];
    float* out = (float*)d_out;

    char* ws = (char*)d_ws;
    const size_t slab = (size_t)XN_ * sizeof(bf16);   // 6291456
    bf16* Xb    = (bf16*)(ws);
    bf16* U     = (bf16*)(ws + slab);
    bf16* Vt    = (bf16*)(ws + 2 * slab);
    bf16* Yw    = (bf16*)(ws + 3 * slab);
    bf16* Wub   = (bf16*)(ws + 4 * slab);
    bf16* Wvb   = (bf16*)(ws + 4 * slab + (size_t)WN_ * 2);
    bf16* Wpb   = (bf16*)(ws + 4 * slab + (size_t)WN_ * 4);
    bf16* PartO = (bf16*)(ws + (size_t)32 * 1024 * 1024);   // 80*24*4096*2 ~ 15.7 MB
    float* PartL = (float*)(ws + (size_t)52 * 1024 * 1024); // 80*24*64*4   ~ 0.5 MB
    int*   Cnt   = (int*)(ws + (size_t)56 * 1024 * 1024);   // 24*32 ints

    dim3 blk(256);
    cvt_all<<<(XN_ + 3 * WN_) / 1024, blk, 0, stream>>>(x, w_u, w_v, w_p, Xb, Wub, Wvb, Wpb, Cnt);

    gemm_uv<<<dim3(M_ / 64, 12), blk, 0, stream>>>(Xb, Wub, Wvb, b_u, b_v, U, Vt);

    flash_part<<<dim3(80, H_, B_), blk, 0, stream>>>(U, Xb, Vt, PartO, PartL, Yw, Cnt);

    gemm_proj<<<dim3(M_ / 64, C_ / 64), blk, 0, stream>>>(Yw, Wpb, b_p, out);
}

// Round 13
// 147.620 us; speedup vs baseline: 3.3144x; 3.3144x over previous
//
#include <hip/hip_runtime.h>
#include <hip/hip_bf16.h>

typedef __hip_bfloat16 bf16;
typedef short bf16x8 __attribute__((ext_vector_type(8)));
typedef short short4v __attribute__((ext_vector_type(4)));
typedef float f32x4 __attribute__((ext_vector_type(4)));

#define B_ 2
#define T_ 2048
#define C_ 768
#define H_ 12
#define HS_ 64
#define M_ (B_ * T_)              // 4096
#define XN_ (B_ * T_ * C_)        // 3145728
#define WN_ (C_ * C_)             // 589824
#define SCALE_ 0.036084391824351615f      // 1/sqrt(768)
#define SCALE_L2E_ 0.05205762071471043f   // SCALE * log2(e)

__device__ inline short bf16bits(float f) {
    union { bf16 b; short s; } u; u.b = __float2bfloat16(f); return u.s;
}

__device__ inline void load_lds16(const void* g, void* l) {
    __builtin_amdgcn_global_load_lds(
        (const __attribute__((address_space(1))) unsigned int*)g,
        (__attribute__((address_space(3))) unsigned int*)l, 16, 0, 0);
}

// fp32 -> bf16 for x, w_u, w_v, w_p in one pass (4 elems/thread)
__global__ __launch_bounds__(256) void cvt_all(
    const float* __restrict__ x,  const float* __restrict__ wu,
    const float* __restrict__ wv, const float* __restrict__ wp,
    bf16* __restrict__ Xb,  bf16* __restrict__ Wub,
    bf16* __restrict__ Wvb, bf16* __restrict__ Wpb)
{
    const long e = (long)(blockIdx.x * 256 + threadIdx.x) * 4;
    const float* src; bf16* dst; long off;
    if (e < XN_)                { src = x;  dst = Xb;  off = e; }
    else if (e < XN_ + WN_)     { src = wu; dst = Wub; off = e - XN_; }
    else if (e < XN_ + 2*WN_)   { src = wv; dst = Wvb; off = e - XN_ - WN_; }
    else                        { src = wp; dst = Wpb; off = e - XN_ - 2L*WN_; }
    f32x4 v = *(const f32x4*)(src + off);
    short4v o;
#pragma unroll
    for (int i = 0; i < 4; ++i) o[i] = bf16bits(v[i]);
    *(short4v*)(dst + off) = o;
}

// sigma^-1 for the PV key permutation: tau bits [u|h|q1 q0|r1 r0] -> [u|q1 q0|h|r1 r0]
__device__ inline int sig_inv(int tau) {
    return (tau & 0x23) | ((tau & 0x10) >> 2) | ((tau & 0x0C) << 1);
}

// Fused U/V projection, 64x128 tile, grid (M/64, 12) = 768 blocks (3/CU).
// by<6 -> U tile scaled by SCALE*log2e (exp2-domain attention);
// by>=6 -> V scattered to sigma/swizzled Vt.
__global__ __launch_bounds__(256) void gemm_uv(
    const bf16* __restrict__ Xb, const bf16* __restrict__ Wu,
    const bf16* __restrict__ Wv, const float* __restrict__ bu,
    const float* __restrict__ bv, bf16* __restrict__ U, bf16* __restrict__ Vt)
{
    __shared__ __align__(16) short tA[64 * 64];    // 8 KB
    __shared__ __align__(16) short tB[128 * 64];   // 16 KB

    const int tid = threadIdx.x;
    const int w = tid >> 6, lane = tid & 63;
    const int nl = lane & 15, quad = lane >> 4;
    const int m0 = blockIdx.x * 64;
    const bool isV = blockIdx.y >= 6;
    const int n0 = (isV ? blockIdx.y - 6 : blockIdx.y) * 128;
    const bf16* Wb = isV ? Wv : Wu;
    const float* bias = isV ? bv : bu;

    f32x4 acc[4][2];
#pragma unroll
    for (int a = 0; a < 4; ++a)
#pragma unroll
        for (int t = 0; t < 2; ++t) acc[a][t] = f32x4{0, 0, 0, 0};

    for (int k0 = 0; k0 < C_; k0 += 64) {
#pragma unroll
        for (int i = 0; i < 2; ++i) {           // A tile: 512 chunks
            const int g = i * 256 + tid;
            const int row = g >> 3, kp = g & 7;
            load_lds16(Xb + (size_t)(m0 + row) * C_ + k0 + (kp ^ (row & 7)) * 8,
                       (char*)tA + g * 16);
        }
#pragma unroll
        for (int i = 0; i < 4; ++i) {           // B tile: 1024 chunks
            const int g = i * 256 + tid;
            const int row = g >> 3, kp = g & 7;
            load_lds16(Wb + (size_t)(n0 + row) * C_ + k0 + (kp ^ (row & 7)) * 8,
                       (char*)tB + g * 16);
        }
        __syncthreads();
#pragma unroll
        for (int half = 0; half < 2; ++half) {
            bf16x8 af[4], bfr[2];
#pragma unroll
            for (int a = 0; a < 4; ++a) {
                const int row = a * 16 + nl;
                af[a] = *(const bf16x8*)((const char*)tA + row * 128 + (((half * 4 + quad) ^ (nl & 7)) * 16));
            }
#pragma unroll
            for (int t = 0; t < 2; ++t) {
                const int row = w * 32 + t * 16 + nl;
                bfr[t] = *(const bf16x8*)((const char*)tB + row * 128 + (((half * 4 + quad) ^ (nl & 7)) * 16));
            }
#pragma unroll
            for (int a = 0; a < 4; ++a)
#pragma unroll
                for (int t = 0; t < 2; ++t)
                    acc[a][t] = __builtin_amdgcn_mfma_f32_16x16x32_bf16(af[a], bfr[t], acc[a][t], 0, 0, 0);
        }
        __syncthreads();
    }

#pragma unroll
    for (int a = 0; a < 4; ++a) {
#pragma unroll
        for (int t = 0; t < 2; ++t) {
            const int col = n0 + w * 32 + t * 16 + nl;
            const float bv_ = bias[col];
#pragma unroll
            for (int r = 0; r < 4; ++r) {
                const int mrow = m0 + a * 16 + quad * 4 + r;
                if (isV) {
                    const float v = acc[a][t][r] + bv_;
                    const int bb = mrow / T_, tt = mrow % T_;
                    const int hh = col / HS_, dd = col % HS_;
                    const int lam = sig_inv(tt & 63);
                    const int pos = (tt & ~63) + (((lam >> 3) ^ (dd & 7)) * 8) + (lam & 7);
                    Vt[(((size_t)bb * H_ + hh) * HS_ + dd) * T_ + pos] = __float2bfloat16(v);
                } else {
                    const float v = (acc[a][t][r] + bv_) * SCALE_L2E_;
                    U[(size_t)mrow * C_ + col] = __float2bfloat16(v);
                }
            }
        }
    }
}

// proj GEMM: 64x64 tile, grid (M/64, C/64) = (64,12) = 768 blocks (3/CU).
__global__ __launch_bounds__(256) void gemm_proj(
    const bf16* __restrict__ A, const bf16* __restrict__ Wb,
    const float* __restrict__ bias, float* __restrict__ Y)
{
    __shared__ __align__(16) short tA[64 * 64];
    __shared__ __align__(16) short tB[64 * 64];

    const int tid = threadIdx.x;
    const int w = tid >> 6, lane = tid & 63;
    const int nl = lane & 15, quad = lane >> 4;
    const int m0 = blockIdx.x * 64, n0 = blockIdx.y * 64;

    f32x4 acc[4];
#pragma unroll
    for (int t = 0; t < 4; ++t) acc[t] = f32x4{0, 0, 0, 0};

    for (int k0 = 0; k0 < C_; k0 += 64) {
#pragma unroll
        for (int i = 0; i < 2; ++i) {
            const int g = i * 256 + tid;
            const int row = g >> 3, kp = g & 7;
            const int kc = (kp ^ (row & 7)) * 8;
            load_lds16(A  + (size_t)(m0 + row) * C_ + k0 + kc, (char*)tA + g * 16);
            load_lds16(Wb + (size_t)(n0 + row) * C_ + k0 + kc, (char*)tB + g * 16);
        }
        __syncthreads();
#pragma unroll
        for (int half = 0; half < 2; ++half) {
            const int row = w * 16 + nl;
            bf16x8 af = *(const bf16x8*)((const char*)tA + row * 128 + (((half * 4 + quad) ^ (nl & 7)) * 16));
#pragma unroll
            for (int t = 0; t < 4; ++t) {
                const int brow = t * 16 + nl;
                bf16x8 bfr = *(const bf16x8*)((const char*)tB + brow * 128 + (((half * 4 + quad) ^ (nl & 7)) * 16));
                acc[t] = __builtin_amdgcn_mfma_f32_16x16x32_bf16(af, bfr, acc[t], 0, 0, 0);
            }
        }
        __syncthreads();
    }

#pragma unroll
    for (int t = 0; t < 4; ++t) {
        const int col = n0 + t * 16 + nl;
        const float bv = bias[col];
#pragma unroll
        for (int r = 0; r < 4; ++r) {
            const int mrow = m0 + w * 16 + quad * 4 + r;
            Y[(size_t)mrow * C_ + col] = acc[t][r] + bv;
        }
    }
}

// Flash partial: block = (64-query tile a, key-chunk c of <=8 K-tiles).
// Additive (O,l) partials; U in exp2 domain so p = v_exp_f32(s) via
// __builtin_amdgcn_exp2f, and the bf16 P pack is round-half-up + v_perm_b32.
// 80 chunks per (b,h), 1920 blocks, heavy first. Single-chunk qtiles (i<8)
// write Yw directly; others write bf16 O partials (l fp32).
// NOTE (r12 post-mortem): do NOT fuse the combine here with device-scope
// fences -- per-block __threadfence() on gfx950 = L2 writeback across
// non-coherent XCDs, serialized the whole device (41 -> 400 us).
__global__ __launch_bounds__(256) void flash_part(
    const bf16* __restrict__ U, const bf16* __restrict__ Xb,
    const bf16* __restrict__ Vt, bf16* __restrict__ PartO,
    float* __restrict__ PartL, bf16* __restrict__ Yw)
{
    __shared__ __align__(16) short kbuf[2][64 * 64];
    __shared__ __align__(16) short vbuf[2][64 * 64];

    const int i = 79 - blockIdx.x;            // heavy chunks first
    int a, c;
    if (i < 8)       { a = i;                c = 0; }
    else if (i < 24) { a = 8  + (i - 8)  / 2; c = (i - 8)  % 2; }
    else if (i < 48) { a = 16 + (i - 24) / 3; c = (i - 24) % 3; }
    else             { a = 24 + (i - 48) / 4; c = (i - 48) % 4; }
    const int kt0 = c * 8, kt1 = min(c * 8 + 7, a);

    const int h = blockIdx.y, b = blockIdx.z;
    const int w = threadIdx.x >> 6, lane = threadIdx.x & 63;
    const int nl = lane & 15, quad = lane >> 4;

    const size_t xbase = (size_t)b * T_ * C_ + (size_t)h * HS_;
    const size_t vtb   = ((size_t)(b * H_ + h)) * HS_ * T_;
    const int q0w = a * 64 + w * 16;

    bf16x8 qb0, qb1;
    {
        const bf16* qp = U + xbase + (size_t)(q0w + nl) * C_;
        qb0 = *(const bf16x8*)(qp + quad * 8);
        qb1 = *(const bf16x8*)(qp + 32 + quad * 8);
    }

    bf16x8 ones;
#pragma unroll
    for (int k = 0; k < 8; ++k) ones[k] = (short)0x3F80;

    f32x4 o[4];
#pragma unroll
    for (int g = 0; g < 4; ++g) o[g] = f32x4{0, 0, 0, 0};
    f32x4 lacc = f32x4{0, 0, 0, 0};

    auto stage = [&](int kt_, int pbuf_) {
        short* kb_ = kbuf[pbuf_]; short* vb_ = vbuf[pbuf_];
#pragma unroll
        for (int i_ = 0; i_ < 2; ++i_) {
            const int g_ = (w * 2 + i_) * 64 + lane;
            const int rw_ = g_ >> 3, kp_ = g_ & 7;
            load_lds16(Xb + xbase + (size_t)(kt_ * 64 + rw_) * C_ + ((kp_ ^ (rw_ & 7)) * 8),
                       (char*)kb_ + (w * 2 + i_) * 1024);
            load_lds16(Vt + vtb + (size_t)rw_ * T_ + kt_ * 64 + kp_ * 8,
                       (char*)vb_ + (w * 2 + i_) * 1024);
        }
    };

    stage(kt0, 0);
    int pb = 0;
    for (int kt = kt0; kt <= kt1; ++kt) {
        __syncthreads();                       // drains stage(kt)
        if (kt < kt1) stage(kt + 1, pb ^ 1);   // prefetch overlaps compute

        const short* kb  = kbuf[pb];
        const short* vbp = vbuf[pb];
        const bool dg = (kt == a);             // diagonal tile (last chunk only)

        // S^T = K.Q^T: lane (quad,nl) reg r = S[key=16t+4quad+r][q=q0w+nl]
        f32x4 s[4];
#pragma unroll
        for (int t = 0; t < 4; ++t) {
            s[t] = f32x4{0, 0, 0, 0};
            if (!dg || t <= w) {
                const int key = t * 16 + nl;
                bf16x8 k0 = *(const bf16x8*)((const char*)kb + key * 128 + (((0 + quad) ^ (nl & 7)) * 16));
                bf16x8 k1 = *(const bf16x8*)((const char*)kb + key * 128 + (((4 + quad) ^ (nl & 7)) * 16));
                s[t] = __builtin_amdgcn_mfma_f32_16x16x32_bf16(k0, qb0, s[t], 0, 0, 0);
                s[t] = __builtin_amdgcn_mfma_f32_16x16x32_bf16(k1, qb1, s[t], 0, 0, 0);
            }
        }

        // p = 2^s via raw v_exp_f32; round-half-up to bf16 and pack pairs
        // with v_perm_b32 (sel 0x07060302 takes the two hi16s).
        unsigned pw[8];
#pragma unroll
        for (int t = 0; t < 4; ++t) {
            float p[4];
#pragma unroll
            for (int r = 0; r < 4; ++r) {
                if (!dg || t <= w) {
                    p[r] = __builtin_amdgcn_exp2f(s[t][r]);
                    if (dg && t == w && (4 * quad + r > nl)) p[r] = 0.f;
                } else {
                    p[r] = 0.f;
                }
            }
#pragma unroll
            for (int hp = 0; hp < 2; ++hp) {
                const unsigned b0 = __float_as_uint(p[hp * 2])     + 0x8000u;
                const unsigned b1 = __float_as_uint(p[hp * 2 + 1]) + 0x8000u;
                pw[t * 2 + hp] = __builtin_amdgcn_perm(b1, b0, 0x07060302u);
            }
        }
        union { unsigned u[4]; bf16x8 v; } cv0, cv1;
#pragma unroll
        for (int k = 0; k < 4; ++k) { cv0.u[k] = pw[k]; cv1.u[k] = pw[4 + k]; }
        const bf16x8 pa0 = cv0.v, pa1 = cv1.v;

        // l += P.1 ; O += P.V (sigma-permuted keys match Vt layout)
        lacc = __builtin_amdgcn_mfma_f32_16x16x32_bf16(pa0, ones, lacc, 0, 0, 0);
        lacc = __builtin_amdgcn_mfma_f32_16x16x32_bf16(pa1, ones, lacc, 0, 0, 0);
#pragma unroll
        for (int g = 0; g < 4; ++g) {
            const int d = g * 16 + nl;
            bf16x8 v0 = *(const bf16x8*)((const char*)vbp + d * 128 + (((0 + quad) ^ (nl & 7)) * 16));
            bf16x8 v1 = *(const bf16x8*)((const char*)vbp + d * 128 + (((4 + quad) ^ (nl & 7)) * 16));
            o[g] = __builtin_amdgcn_mfma_f32_16x16x32_bf16(pa0, v0, o[g], 0, 0, 0);
            o[g] = __builtin_amdgcn_mfma_f32_16x16x32_bf16(pa1, v1, o[g], 0, 0, 0);
        }
        pb ^= 1;
    }

    if (i < 8) {
        // single chunk: normalize and write Yw directly (token-major)
#pragma unroll
        for (int r = 0; r < 4; ++r) {
            const float inv_l = 1.f / lacc[r];
            const size_t yrow = xbase + (size_t)(q0w + quad * 4 + r) * C_;
#pragma unroll
            for (int g = 0; g < 4; ++g)
                Yw[yrow + g * 16 + nl] = __float2bfloat16(o[g][r] * inv_l);
        }
    } else {
        // bf16 O partial (64x64) + fp32 l (64)
        bf16* slot = PartO + (size_t)((b * H_ + h) * 80 + i) * 4096;
#pragma unroll
        for (int g = 0; g < 4; ++g)
#pragma unroll
            for (int r = 0; r < 4; ++r)
                slot[(w * 16 + quad * 4 + r) * 64 + g * 16 + nl] = __float2bfloat16(o[g][r]);
        if (nl == 0) {
            float* lslot = PartL + (size_t)((b * H_ + h) * 80 + i) * 64;
#pragma unroll
            for (int r = 0; r < 4; ++r)
                lslot[w * 16 + quad * 4 + r] = lacc[r];
        }
    }
}

// Combine partials for qtiles a in [8,32): grid (24, 12, 2). Sums 2..4
// bf16 O chunks + fp32 l, divides, writes bf16 Yw token-major.
__global__ __launch_bounds__(256) void combine(
    const bf16* __restrict__ PartO, const float* __restrict__ PartL,
    bf16* __restrict__ Yw)
{
    const int a = 8 + blockIdx.x;             // 8..31
    const int h = blockIdx.y, b = blockIdx.z;
    const int nch = (a >> 3) + 1;             // 2,3,4
    const int base = (a < 16) ? 8  + (a - 8)  * 2
                   : (a < 24) ? 24 + (a - 16) * 3
                   :            48 + (a - 24) * 4;
    const int tid = threadIdx.x;
    const int q = tid >> 2, d0 = (tid & 3) * 16;
    const size_t bh80 = (size_t)(b * H_ + h) * 80 + base;

    float acc[16];
#pragma unroll
    for (int j = 0; j < 16; ++j) acc[j] = 0.f;
    float l = 0.f;
    for (int cc = 0; cc < nch; ++cc) {
        const bf16* sp = PartO + (bh80 + cc) * 4096 + q * 64 + d0;
#pragma unroll
        for (int v = 0; v < 2; ++v) {
            bf16x8 pk = *(const bf16x8*)(sp + v * 8);
#pragma unroll
            for (int k = 0; k < 8; ++k) {
                union { short s; bf16 b; } u; u.s = pk[k];
                acc[v * 8 + k] += __bfloat162float(u.b);
            }
        }
        l += PartL[(bh80 + cc) * 64 + q];
    }
    const float inv = 1.f / l;
    bf16* yp = Yw + ((size_t)(b * T_ + a * 64 + q)) * C_ + h * HS_ + d0;
#pragma unroll
    for (int v = 0; v < 4; ++v) {
        short4v ov;
#pragma unroll
        for (int k = 0; k < 4; ++k) ov[k] = bf16bits(acc[v * 4 + k] * inv);
        *(short4v*)(yp + v * 4) = ov;
    }
}

extern "C" void kernel_launch(void* const* d_in, const int* in_sizes, int n_in,
                              void* d_out, int out_size, void* d_ws, size_t ws_size,
                              hipStream_t stream) {
    const float* x   = (const float*)d_in[0];
    const float* w_u = (const float*)d_in[1];
    const float* b_u = (const float*)d_in[2];
    const float* w_v = (const float*)d_in[3];
    const float* b_v = (const float*)d_in[4];
    const float* w_p = (const float*)d_in[5];
    const float* b_p = (const float*)d_in[6];
    float* out = (float*)d_out;

    char* ws = (char*)d_ws;
    const size_t slab = (size_t)XN_ * sizeof(bf16);   // 6291456
    bf16* Xb    = (bf16*)(ws);
    bf16* U     = (bf16*)(ws + slab);
    bf16* Vt    = (bf16*)(ws + 2 * slab);
    bf16* Yw    = (bf16*)(ws + 3 * slab);
    bf16* Wub   = (bf16*)(ws + 4 * slab);
    bf16* Wvb   = (bf16*)(ws + 4 * slab + (size_t)WN_ * 2);
    bf16* Wpb   = (bf16*)(ws + 4 * slab + (size_t)WN_ * 4);
    bf16* PartO = (bf16*)(ws + (size_t)32 * 1024 * 1024);   // 80*24*4096*2 ~ 15.7 MB
    float* PartL = (float*)(ws + (size_t)52 * 1024 * 1024); // 80*24*64*4   ~ 0.5 MB

    dim3 blk(256);
    cvt_all<<<(XN_ + 3 * WN_) / 1024, blk, 0, stream>>>(x, w_u, w_v, w_p, Xb, Wub, Wvb, Wpb);

    gemm_uv<<<dim3(M_ / 64, 12), blk, 0, stream>>>(Xb, Wub, Wvb, b_u, b_v, U, Vt);

    flash_part<<<dim3(80, H_, B_), blk, 0, stream>>>(U, Xb, Vt, PartO, PartL, Yw);
    combine<<<dim3(24, H_, B_), blk, 0, stream>>>(PartO, PartL, Yw);

    gemm_proj<<<dim3(M_ / 64, C_ / 64), blk, 0, stream>>>(Yw, Wpb, b_p, out);
}

// Round 14
// 145.636 us; speedup vs baseline: 3.3596x; 1.0136x over previous
//
#include <hip/hip_runtime.h>
#include <hip/hip_bf16.h>

typedef __hip_bfloat16 bf16;
typedef short bf16x8 __attribute__((ext_vector_type(8)));
typedef short short4v __attribute__((ext_vector_type(4)));
typedef float f32x4 __attribute__((ext_vector_type(4)));

#define B_ 2
#define T_ 2048
#define C_ 768
#define H_ 12
#define HS_ 64
#define M_ (B_ * T_)              // 4096
#define XN_ (B_ * T_ * C_)        // 3145728
#define WN_ (C_ * C_)             // 589824
#define SCALE_ 0.036084391824351615f      // 1/sqrt(768)
#define SCALE_L2E_ 0.05205762071471043f   // SCALE * log2(e)

__device__ inline short bf16bits(float f) {
    union { bf16 b; short s; } u; u.b = __float2bfloat16(f); return u.s;
}

__device__ inline void load_lds16(const void* g, void* l) {
    __builtin_amdgcn_global_load_lds(
        (const __attribute__((address_space(1))) unsigned int*)g,
        (__attribute__((address_space(3))) unsigned int*)l, 16, 0, 0);
}

// fp32 -> bf16 for x, w_u, w_v, w_p in one pass (4 elems/thread)
__global__ __launch_bounds__(256) void cvt_all(
    const float* __restrict__ x,  const float* __restrict__ wu,
    const float* __restrict__ wv, const float* __restrict__ wp,
    bf16* __restrict__ Xb,  bf16* __restrict__ Wub,
    bf16* __restrict__ Wvb, bf16* __restrict__ Wpb)
{
    const long e = (long)(blockIdx.x * 256 + threadIdx.x) * 4;
    const float* src; bf16* dst; long off;
    if (e < XN_)                { src = x;  dst = Xb;  off = e; }
    else if (e < XN_ + WN_)     { src = wu; dst = Wub; off = e - XN_; }
    else if (e < XN_ + 2*WN_)   { src = wv; dst = Wvb; off = e - XN_ - WN_; }
    else                        { src = wp; dst = Wpb; off = e - XN_ - 2L*WN_; }
    f32x4 v = *(const f32x4*)(src + off);
    short4v o;
#pragma unroll
    for (int i = 0; i < 4; ++i) o[i] = bf16bits(v[i]);
    *(short4v*)(dst + off) = o;
}

// sigma^-1 for the PV key permutation: tau bits [u|h|q1 q0|r1 r0] -> [u|q1 q0|h|r1 r0]
__device__ inline int sig_inv(int tau) {
    return (tau & 0x23) | ((tau & 0x10) >> 2) | ((tau & 0x0C) << 1);
}

// Fused U/V projection, 64x128 tile, BK=128 (6 K-iters, half the barriers
// of BK=64; LDS 48 KB -> still 3 blocks/CU = grid residency, no occupancy
// loss). by<6 -> U tile scaled by SCALE*log2e; by>=6 -> V scattered to
// sigma/swizzled Vt. Rows are 256 B; chunk swizzle kp^(row&7) keeps the
// 2-way-free bank pattern (bank = 4*chunk mod 32, row stride = 0 mod 128B).
__global__ __launch_bounds__(256) void gemm_uv(
    const bf16* __restrict__ Xb, const bf16* __restrict__ Wu,
    const bf16* __restrict__ Wv, const float* __restrict__ bu,
    const float* __restrict__ bv, bf16* __restrict__ U, bf16* __restrict__ Vt)
{
    __shared__ __align__(16) short tA[64 * 128];    // 16 KB
    __shared__ __align__(16) short tB[128 * 128];   // 32 KB

    const int tid = threadIdx.x;
    const int w = tid >> 6, lane = tid & 63;
    const int nl = lane & 15, quad = lane >> 4;
    const int m0 = blockIdx.x * 64;
    const bool isV = blockIdx.y >= 6;
    const int n0 = (isV ? blockIdx.y - 6 : blockIdx.y) * 128;
    const bf16* Wb = isV ? Wv : Wu;
    const float* bias = isV ? bv : bu;

    f32x4 acc[4][2];
#pragma unroll
    for (int a = 0; a < 4; ++a)
#pragma unroll
        for (int t = 0; t < 2; ++t) acc[a][t] = f32x4{0, 0, 0, 0};

    for (int k0 = 0; k0 < C_; k0 += 128) {
#pragma unroll
        for (int i = 0; i < 4; ++i) {           // A tile: 1024 chunks
            const int g = i * 256 + tid;
            const int row = g >> 4, kp = g & 15;
            load_lds16(Xb + (size_t)(m0 + row) * C_ + k0 + (kp ^ (row & 7)) * 8,
                       (char*)tA + g * 16);
        }
#pragma unroll
        for (int i = 0; i < 8; ++i) {           // B tile: 2048 chunks
            const int g = i * 256 + tid;
            const int row = g >> 4, kp = g & 15;
            load_lds16(Wb + (size_t)(n0 + row) * C_ + k0 + (kp ^ (row & 7)) * 8,
                       (char*)tB + g * 16);
        }
        __syncthreads();
#pragma unroll
        for (int half = 0; half < 4; ++half) {
            bf16x8 af[4], bfr[2];
#pragma unroll
            for (int a = 0; a < 4; ++a) {
                const int row = a * 16 + nl;
                af[a] = *(const bf16x8*)((const char*)tA + row * 256 + (((half * 4 + quad) ^ (nl & 7)) * 16));
            }
#pragma unroll
            for (int t = 0; t < 2; ++t) {
                const int row = w * 32 + t * 16 + nl;
                bfr[t] = *(const bf16x8*)((const char*)tB + row * 256 + (((half * 4 + quad) ^ (nl & 7)) * 16));
            }
#pragma unroll
            for (int a = 0; a < 4; ++a)
#pragma unroll
                for (int t = 0; t < 2; ++t)
                    acc[a][t] = __builtin_amdgcn_mfma_f32_16x16x32_bf16(af[a], bfr[t], acc[a][t], 0, 0, 0);
        }
        __syncthreads();
    }

#pragma unroll
    for (int a = 0; a < 4; ++a) {
#pragma unroll
        for (int t = 0; t < 2; ++t) {
            const int col = n0 + w * 32 + t * 16 + nl;
            const float bv_ = bias[col];
#pragma unroll
            for (int r = 0; r < 4; ++r) {
                const int mrow = m0 + a * 16 + quad * 4 + r;
                if (isV) {
                    const float v = acc[a][t][r] + bv_;
                    const int bb = mrow / T_, tt = mrow % T_;
                    const int hh = col / HS_, dd = col % HS_;
                    const int lam = sig_inv(tt & 63);
                    const int pos = (tt & ~63) + (((lam >> 3) ^ (dd & 7)) * 8) + (lam & 7);
                    Vt[(((size_t)bb * H_ + hh) * HS_ + dd) * T_ + pos] = __float2bfloat16(v);
                } else {
                    const float v = (acc[a][t][r] + bv_) * SCALE_L2E_;
                    U[(size_t)mrow * C_ + col] = __float2bfloat16(v);
                }
            }
        }
    }
}

// proj GEMM: 64x64 tile, BK=128 (6 K-iters), grid (M/64, C/64) = 768 blocks.
__global__ __launch_bounds__(256) void gemm_proj(
    const bf16* __restrict__ A, const bf16* __restrict__ Wb,
    const float* __restrict__ bias, float* __restrict__ Y)
{
    __shared__ __align__(16) short tA[64 * 128];   // 16 KB
    __shared__ __align__(16) short tB[64 * 128];   // 16 KB

    const int tid = threadIdx.x;
    const int w = tid >> 6, lane = tid & 63;
    const int nl = lane & 15, quad = lane >> 4;
    const int m0 = blockIdx.x * 64, n0 = blockIdx.y * 64;

    f32x4 acc[4];
#pragma unroll
    for (int t = 0; t < 4; ++t) acc[t] = f32x4{0, 0, 0, 0};

    for (int k0 = 0; k0 < C_; k0 += 128) {
#pragma unroll
        for (int i = 0; i < 4; ++i) {           // A/B tiles: 1024 chunks each
            const int g = i * 256 + tid;
            const int row = g >> 4, kp = g & 15;
            const int kc = (kp ^ (row & 7)) * 8;
            load_lds16(A  + (size_t)(m0 + row) * C_ + k0 + kc, (char*)tA + g * 16);
            load_lds16(Wb + (size_t)(n0 + row) * C_ + k0 + kc, (char*)tB + g * 16);
        }
        __syncthreads();
#pragma unroll
        for (int half = 0; half < 4; ++half) {
            const int row = w * 16 + nl;
            bf16x8 af = *(const bf16x8*)((const char*)tA + row * 256 + (((half * 4 + quad) ^ (nl & 7)) * 16));
#pragma unroll
            for (int t = 0; t < 4; ++t) {
                const int brow = t * 16 + nl;
                bf16x8 bfr = *(const bf16x8*)((const char*)tB + brow * 256 + (((half * 4 + quad) ^ (nl & 7)) * 16));
                acc[t] = __builtin_amdgcn_mfma_f32_16x16x32_bf16(af, bfr, acc[t], 0, 0, 0);
            }
        }
        __syncthreads();
    }

#pragma unroll
    for (int t = 0; t < 4; ++t) {
        const int col = n0 + t * 16 + nl;
        const float bv = bias[col];
#pragma unroll
        for (int r = 0; r < 4; ++r) {
            const int mrow = m0 + w * 16 + quad * 4 + r;
            Y[(size_t)mrow * C_ + col] = acc[t][r] + bv;
        }
    }
}

// Flash partial: block = (64-query tile a, key-chunk c of <=8 K-tiles).
// Additive (O,l) partials; U in exp2 domain so p = v_exp_f32(s) via
// __builtin_amdgcn_exp2f, and the bf16 P pack is round-half-up + v_perm_b32.
// 80 chunks per (b,h), 1920 blocks, heavy first. Single-chunk qtiles (i<8)
// write Yw directly; others write bf16 O partials (l fp32).
// NOTE (r12 post-mortem): do NOT fuse the combine here with device-scope
// fences -- per-block __threadfence() on gfx950 = L2 writeback across
// non-coherent XCDs, serialized the whole device (41 -> 400 us).
__global__ __launch_bounds__(256) void flash_part(
    const bf16* __restrict__ U, const bf16* __restrict__ Xb,
    const bf16* __restrict__ Vt, bf16* __restrict__ PartO,
    float* __restrict__ PartL, bf16* __restrict__ Yw)
{
    __shared__ __align__(16) short kbuf[2][64 * 64];
    __shared__ __align__(16) short vbuf[2][64 * 64];

    const int i = 79 - blockIdx.x;            // heavy chunks first
    int a, c;
    if (i < 8)       { a = i;                c = 0; }
    else if (i < 24) { a = 8  + (i - 8)  / 2; c = (i - 8)  % 2; }
    else if (i < 48) { a = 16 + (i - 24) / 3; c = (i - 24) % 3; }
    else             { a = 24 + (i - 48) / 4; c = (i - 48) % 4; }
    const int kt0 = c * 8, kt1 = min(c * 8 + 7, a);

    const int h = blockIdx.y, b = blockIdx.z;
    const int w = threadIdx.x >> 6, lane = threadIdx.x & 63;
    const int nl = lane & 15, quad = lane >> 4;

    const size_t xbase = (size_t)b * T_ * C_ + (size_t)h * HS_;
    const size_t vtb   = ((size_t)(b * H_ + h)) * HS_ * T_;
    const int q0w = a * 64 + w * 16;

    bf16x8 qb0, qb1;
    {
        const bf16* qp = U + xbase + (size_t)(q0w + nl) * C_;
        qb0 = *(const bf16x8*)(qp + quad * 8);
        qb1 = *(const bf16x8*)(qp + 32 + quad * 8);
    }

    bf16x8 ones;
#pragma unroll
    for (int k = 0; k < 8; ++k) ones[k] = (short)0x3F80;

    f32x4 o[4];
#pragma unroll
    for (int g = 0; g < 4; ++g) o[g] = f32x4{0, 0, 0, 0};
    f32x4 lacc = f32x4{0, 0, 0, 0};

    auto stage = [&](int kt_, int pbuf_) {
        short* kb_ = kbuf[pbuf_]; short* vb_ = vbuf[pbuf_];
#pragma unroll
        for (int i_ = 0; i_ < 2; ++i_) {
            const int g_ = (w * 2 + i_) * 64 + lane;
            const int rw_ = g_ >> 3, kp_ = g_ & 7;
            load_lds16(Xb + xbase + (size_t)(kt_ * 64 + rw_) * C_ + ((kp_ ^ (rw_ & 7)) * 8),
                       (char*)kb_ + (w * 2 + i_) * 1024);
            load_lds16(Vt + vtb + (size_t)rw_ * T_ + kt_ * 64 + kp_ * 8,
                       (char*)vb_ + (w * 2 + i_) * 1024);
        }
    };

    stage(kt0, 0);
    int pb = 0;
    for (int kt = kt0; kt <= kt1; ++kt) {
        __syncthreads();                       // drains stage(kt)
        if (kt < kt1) stage(kt + 1, pb ^ 1);   // prefetch overlaps compute

        const short* kb  = kbuf[pb];
        const short* vbp = vbuf[pb];
        const bool dg = (kt == a);             // diagonal tile (last chunk only)

        // S^T = K.Q^T: lane (quad,nl) reg r = S[key=16t+4quad+r][q=q0w+nl]
        f32x4 s[4];
#pragma unroll
        for (int t = 0; t < 4; ++t) {
            s[t] = f32x4{0, 0, 0, 0};
            if (!dg || t <= w) {
                const int key = t * 16 + nl;
                bf16x8 k0 = *(const bf16x8*)((const char*)kb + key * 128 + (((0 + quad) ^ (nl & 7)) * 16));
                bf16x8 k1 = *(const bf16x8*)((const char*)kb + key * 128 + (((4 + quad) ^ (nl & 7)) * 16));
                s[t] = __builtin_amdgcn_mfma_f32_16x16x32_bf16(k0, qb0, s[t], 0, 0, 0);
                s[t] = __builtin_amdgcn_mfma_f32_16x16x32_bf16(k1, qb1, s[t], 0, 0, 0);
            }
        }

        // p = 2^s via raw v_exp_f32; round-half-up to bf16 and pack pairs
        // with v_perm_b32 (sel 0x07060302 takes the two hi16s).
        unsigned pw[8];
#pragma unroll
        for (int t = 0; t < 4; ++t) {
            float p[4];
#pragma unroll
            for (int r = 0; r < 4; ++r) {
                if (!dg || t <= w) {
                    p[r] = __builtin_amdgcn_exp2f(s[t][r]);
                    if (dg && t == w && (4 * quad + r > nl)) p[r] = 0.f;
                } else {
                    p[r] = 0.f;
                }
            }
#pragma unroll
            for (int hp = 0; hp < 2; ++hp) {
                const unsigned b0 = __float_as_uint(p[hp * 2])     + 0x8000u;
                const unsigned b1 = __float_as_uint(p[hp * 2 + 1]) + 0x8000u;
                pw[t * 2 + hp] = __builtin_amdgcn_perm(b1, b0, 0x07060302u);
            }
        }
        union { unsigned u[4]; bf16x8 v; } cv0, cv1;
#pragma unroll
        for (int k = 0; k < 4; ++k) { cv0.u[k] = pw[k]; cv1.u[k] = pw[4 + k]; }
        const bf16x8 pa0 = cv0.v, pa1 = cv1.v;

        // l += P.1 ; O += P.V (sigma-permuted keys match Vt layout)
        lacc = __builtin_amdgcn_mfma_f32_16x16x32_bf16(pa0, ones, lacc, 0, 0, 0);
        lacc = __builtin_amdgcn_mfma_f32_16x16x32_bf16(pa1, ones, lacc, 0, 0, 0);
#pragma unroll
        for (int g = 0; g < 4; ++g) {
            const int d = g * 16 + nl;
            bf16x8 v0 = *(const bf16x8*)((const char*)vbp + d * 128 + (((0 + quad) ^ (nl & 7)) * 16));
            bf16x8 v1 = *(const bf16x8*)((const char*)vbp + d * 128 + (((4 + quad) ^ (nl & 7)) * 16));
            o[g] = __builtin_amdgcn_mfma_f32_16x16x32_bf16(pa0, v0, o[g], 0, 0, 0);
            o[g] = __builtin_amdgcn_mfma_f32_16x16x32_bf16(pa1, v1, o[g], 0, 0, 0);
        }
        pb ^= 1;
    }

    if (i < 8) {
        // single chunk: normalize and write Yw directly (token-major)
#pragma unroll
        for (int r = 0; r < 4; ++r) {
            const float inv_l = 1.f / lacc[r];
            const size_t yrow = xbase + (size_t)(q0w + quad * 4 + r) * C_;
#pragma unroll
            for (int g = 0; g < 4; ++g)
                Yw[yrow + g * 16 + nl] = __float2bfloat16(o[g][r] * inv_l);
        }
    } else {
        // bf16 O partial (64x64) + fp32 l (64)
        bf16* slot = PartO + (size_t)((b * H_ + h) * 80 + i) * 4096;
#pragma unroll
        for (int g = 0; g < 4; ++g)
#pragma unroll
            for (int r = 0; r < 4; ++r)
                slot[(w * 16 + quad * 4 + r) * 64 + g * 16 + nl] = __float2bfloat16(o[g][r]);
        if (nl == 0) {
            float* lslot = PartL + (size_t)((b * H_ + h) * 80 + i) * 64;
#pragma unroll
            for (int r = 0; r < 4; ++r)
                lslot[w * 16 + quad * 4 + r] = lacc[r];
        }
    }
}

// Combine partials for qtiles a in [8,32): grid (24, 12, 2). Sums 2..4
// bf16 O chunks + fp32 l, divides, writes bf16 Yw token-major.
__global__ __launch_bounds__(256) void combine(
    const bf16* __restrict__ PartO, const float* __restrict__ PartL,
    bf16* __restrict__ Yw)
{
    const int a = 8 + blockIdx.x;             // 8..31
    const int h = blockIdx.y, b = blockIdx.z;
    const int nch = (a >> 3) + 1;             // 2,3,4
    const int base = (a < 16) ? 8  + (a - 8)  * 2
                   : (a < 24) ? 24 + (a - 16) * 3
                   :            48 + (a - 24) * 4;
    const int tid = threadIdx.x;
    const int q = tid >> 2, d0 = (tid & 3) * 16;
    const size_t bh80 = (size_t)(b * H_ + h) * 80 + base;

    float acc[16];
#pragma unroll
    for (int j = 0; j < 16; ++j) acc[j] = 0.f;
    float l = 0.f;
    for (int cc = 0; cc < nch; ++cc) {
        const bf16* sp = PartO + (bh80 + cc) * 4096 + q * 64 + d0;
#pragma unroll
        for (int v = 0; v < 2; ++v) {
            bf16x8 pk = *(const bf16x8*)(sp + v * 8);
#pragma unroll
            for (int k = 0; k < 8; ++k) {
                union { short s; bf16 b; } u; u.s = pk[k];
                acc[v * 8 + k] += __bfloat162float(u.b);
            }
        }
        l += PartL[(bh80 + cc) * 64 + q];
    }
    const float inv = 1.f / l;
    bf16* yp = Yw + ((size_t)(b * T_ + a * 64 + q)) * C_ + h * HS_ + d0;
#pragma unroll
    for (int v = 0; v < 4; ++v) {
        short4v ov;
#pragma unroll
        for (int k = 0; k < 4; ++k) ov[k] = bf16bits(acc[v * 4 + k] * inv);
        *(short4v*)(yp + v * 4) = ov;
    }
}

extern "C" void kernel_launch(void* const* d_in, const int* in_sizes, int n_in,
                              void* d_out, int out_size, void* d_ws, size_t ws_size,
                              hipStream_t stream) {
    const float* x   = (const float*)d_in[0];
    const float* w_u = (const float*)d_in[1];
    const float* b_u = (const float*)d_in[2];
    const float* w_v = (const float*)d_in[3];
    const float* b_v = (const float*)d_in[4];
    const float* w_p = (const float*)d_in[5];
    const float* b_p = (const float*)d_in[6];
    float* out = (float*)d_out;

    char* ws = (char*)d_ws;
    const size_t slab = (size_t)XN_ * sizeof(bf16);   // 6291456
    bf16* Xb    = (bf16*)(ws);
    bf16* U     = (bf16*)(ws + slab);
    bf16* Vt    = (bf16*)(ws + 2 * slab);
    bf16* Yw    = (bf16*)(ws + 3 * slab);
    bf16* Wub   = (bf16*)(ws + 4 * slab);
    bf16* Wvb   = (bf16*)(ws + 4 * slab + (size_t)WN_ * 2);
    bf16* Wpb   = (bf16*)(ws + 4 * slab + (size_t)WN_ * 4);
    bf16* PartO = (bf16*)(ws + (size_t)32 * 1024 * 1024);   // 80*24*4096*2 ~ 15.7 MB
    float* PartL = (float*)(ws + (size_t)52 * 1024 * 1024); // 80*24*64*4   ~ 0.5 MB

    dim3 blk(256);
    cvt_all<<<(XN_ + 3 * WN_) / 1024, blk, 0, stream>>>(x, w_u, w_v, w_p, Xb, Wub, Wvb, Wpb);

    gemm_uv<<<dim3(M_ / 64, 12), blk, 0, stream>>>(Xb, Wub, Wvb, b_u, b_v, U, Vt);

    flash_part<<<dim3(80, H_, B_), blk, 0, stream>>>(U, Xb, Vt, PartO, PartL, Yw);
    combine<<<dim3(24, H_, B_), blk, 0, stream>>>(PartO, PartL, Yw);

    gemm_proj<<<dim3(M_ / 64, C_ / 64), blk, 0, stream>>>(Yw, Wpb, b_p, out);
}